// Round 1
// baseline (761.356 us; speedup 1.0000x reference)
//
#include <hip/hip_runtime.h>
#include <stdint.h>

#pragma clang fp contract(off)

#define B_ 2
#define P_ 512
#define C_ 21
#define CF 20            // foreground classes
#define DET 100
#define SCORE_THRESH 0.05f
#define NMS_THR 0.5f
#define BBOX_CLIP 4.135166556742356f   // log(1000/16)

typedef unsigned long long u64;
typedef unsigned int u32;

// order-preserving float<->uint mapping (ascending uint == ascending float)
__device__ __forceinline__ u32 f2o(float f) {
  u32 u = __float_as_uint(f);
  return (u & 0x80000000u) ? ~u : (u | 0x80000000u);
}
__device__ __forceinline__ float o2f(u32 o) {
  u32 u = (o & 0x80000000u) ? (o ^ 0x80000000u) : ~o;
  return __uint_as_float(u);
}

// ---------------------------------------------------------------------------
// K1: softmax score + rotated decode + corner pts + clipped AABB
// one thread per (proposal n, fg class cf)
// ---------------------------------------------------------------------------
__global__ void decode_kernel(const float* __restrict__ logits,
                              const float* __restrict__ breg,
                              const float* __restrict__ rrects,
                              float* __restrict__ smsk,   // [B*CF*P] masked score
                              float* __restrict__ pr5,    // [B*CF*P][5]
                              float* __restrict__ bb4,    // [B*CF*P][4]
                              float* __restrict__ pts8) { // [B*CF*P][8] x0..3,y0..3
  int idx = blockIdx.x * blockDim.x + threadIdx.x;
  if (idx >= B_ * P_ * CF) return;
  int n = idx / CF;
  int cf = idx % CF;
  int c = cf + 1;
  int b = n / P_, p = n % P_;

  // softmax over 21 classes (max-subtracted, like jax.nn.softmax)
  const float* lg = logits + n * C_;
  float mx = lg[0];
  for (int k = 1; k < C_; ++k) mx = fmaxf(mx, lg[k]);
  float den = 0.f;
  for (int k = 0; k < C_; ++k) den += expf(lg[k] - mx);
  float sc = expf(lg[c] - mx) / den;

  // decode (weights 10,10,5,5,3)
  const float* d = breg + n * (C_ * 5) + c * 5;
  float dx = d[0] / 10.0f, dy = d[1] / 10.0f;
  float dw = d[2] / 5.0f, dh = d[3] / 5.0f, da = d[4] / 3.0f;
  dw = fminf(dw, BBOX_CLIP);
  dh = fminf(dh, BBOX_CLIP);
  const float* an = rrects + n * 5;
  float xc = an[0], yc = an[1], w = an[2], h = an[3], a = an[4];
  float px = dx * w + xc;
  float py = dy * h + yc;
  float pw = expf(dw) * w;
  float ph = expf(dh) * h;
  float pa = da * 57.29577951308232f + a;   // 180/pi

  int gi = (b * CF + cf) * P_ + p;
  pr5[gi * 5 + 0] = px; pr5[gi * 5 + 1] = py;
  pr5[gi * 5 + 2] = pw; pr5[gi * 5 + 3] = ph; pr5[gi * 5 + 4] = pa;

  // corner points (CCW), min/max -> clipped AABB
  float t = pa * 0.017453292519943295f;     // pi/180
  float cs = cosf(t), sn = sinf(t);
  float hx = pw * 0.5f, hy = ph * 0.5f;
  float ox[4] = {-hx, hx, hx, -hx};
  float oy[4] = {-hy, -hy, hy, hy};
  float minx = 1e30f, miny = 1e30f, maxx = -1e30f, maxy = -1e30f;
  for (int q = 0; q < 4; ++q) {
    float x = px + cs * ox[q] - sn * oy[q];
    float y = py + sn * ox[q] + cs * oy[q];
    pts8[gi * 8 + q] = x;
    pts8[gi * 8 + 4 + q] = y;
    minx = fminf(minx, x); maxx = fmaxf(maxx, x);
    miny = fminf(miny, y); maxy = fmaxf(maxy, y);
  }
  bb4[gi * 4 + 0] = fminf(fmaxf(minx, 0.f), 1023.0f);
  bb4[gi * 4 + 1] = fminf(fmaxf(miny, 0.f), 799.0f);
  bb4[gi * 4 + 2] = fminf(fmaxf(maxx, 0.f), 1023.0f);
  bb4[gi * 4 + 3] = fminf(fmaxf(maxy, 0.f), 799.0f);

  bool valid = sc > SCORE_THRESH;
  smsk[gi] = valid ? sc : -1.0f;
}

// ---------------------------------------------------------------------------
// K2: per-(image,class) descending sort of 512 masked scores, stable tie->lower idx
// ---------------------------------------------------------------------------
__global__ void sort_kernel(const float* __restrict__ smsk,
                            float* __restrict__ scs, int* __restrict__ sord) {
  int g = blockIdx.x;
  int tid = threadIdx.x;
  __shared__ u64 key[P_];
  for (int i = tid; i < P_; i += 256) {
    float v = smsk[g * P_ + i];
    key[i] = ((u64)f2o(v) << 32) | (u32)(~(u32)i);
  }
  __syncthreads();
  for (int k = 2; k <= P_; k <<= 1) {
    for (int j = k >> 1; j > 0; j >>= 1) {
      for (int i = tid; i < P_; i += 256) {
        int ixj = i ^ j;
        if (ixj > i) {
          bool desc = ((i & k) == 0);
          u64 a = key[i], b = key[ixj];
          bool sw = desc ? (a < b) : (a > b);
          if (sw) { key[i] = b; key[ixj] = a; }
        }
      }
      __syncthreads();
    }
  }
  for (int i = tid; i < P_; i += 256) {
    u64 kk = key[i];
    scs[g * P_ + i] = o2f((u32)(kk >> 32));
    sord[g * P_ + i] = (int)(~(u32)kk);
  }
}

// ---------------------------------------------------------------------------
// exact convex quad-quad intersection area, replicating reference arithmetic
// poly (qx,qy) clipped by edges of (rx,ry)
// ---------------------------------------------------------------------------
__device__ float inter_area_dev(const float* qx, const float* qy,
                                const float* rx, const float* ry) {
  float ax_[8], ay_[8], bx_[8], by_[8];
  int n = 4;
  for (int t = 0; t < 8; ++t) {
    ax_[t] = (t < 4) ? qx[t] : 0.f;
    ay_[t] = (t < 4) ? qy[t] : 0.f;
  }
  float* inx = ax_; float* iny = ay_;
  float* outx = bx_; float* outy = by_;
  for (int e = 0; e < 4; ++e) {
    float a0 = rx[e], a1 = ry[e];
    float b0 = rx[(e + 1) & 3], b1 = ry[(e + 1) & 3];
    float dx = b0 - a0, dy = b1 - a1;
    int m = 0;
    int nn = (n > 1) ? n : 1;
    for (int t = 0; t < 8; ++t) { outx[t] = 0.f; outy[t] = 0.f; }
    for (int t = 0; t < 8; ++t) {
      bool act = t < n;
      float sx = inx[t], sy = iny[t];
      int ei = (t + 1) % nn; if (ei > 7) ei = 7;
      float ex = inx[ei], ey = iny[ei];
      float cs = dx * (sy - a1) - dy * (sx - a0);
      float ce = dx * (ey - a1) - dy * (ex - a0);
      float denom = cs - ce;
      float dn = (fabsf(denom) > 1e-12f) ? denom : 1e-12f;
      float tt = cs / dn;
      float ipx = sx + tt * (ex - sx);
      float ipy = sy + tt * (ey - sy);
      bool s_in = cs >= 0.f, e_in = ce >= 0.f;
      bool app1 = act && (s_in != e_in);
      if (app1 && m < 8) { outx[m] = ipx; outy[m] = ipy; }
      if (app1) ++m;
      bool app2 = act && e_in;
      if (app2 && m < 8) { outx[m] = ex; outy[m] = ey; }
      if (app2) ++m;
    }
    n = m;
    float* tx = inx; inx = outx; outx = tx;
    float* ty = iny; iny = outy; outy = ty;
  }
  int nn = (n > 1) ? n : 1;
  float s = 0.f;
  for (int t = 0; t < 8; ++t) {
    if (t < n) {
      int nx = (t + 1) % nn; if (nx > 7) nx = 7;
      s += inx[t] * iny[nx] - inx[nx] * iny[t];
    }
  }
  float area = 0.5f * fabsf(s);
  return (n >= 3) ? area : 0.f;
}

// ---------------------------------------------------------------------------
// K3: per-(image,class) NMS. Parallel suppression bitmatrix over the valid
// prefix, then one-wave sequential greedy; emit first 100 kept as candidates.
// ---------------------------------------------------------------------------
__global__ void nms_kernel(const float* __restrict__ scs, const int* __restrict__ sord,
                           const float* __restrict__ pr5, const float* __restrict__ pts8,
                           u64* __restrict__ cand) {
  int g = blockIdx.x;        // b*CF + cls
  int tid = threadIdx.x;
  __shared__ float spx[P_][4];
  __shared__ float spy[P_][4];
  __shared__ float sarea[P_];
  __shared__ u64 ssup[P_][8];
  __shared__ int sV;
  __shared__ u64 skeep[8];
  if (tid == 0) sV = 0;
  __syncthreads();
  for (int r = tid; r < P_; r += 256) {
    int p = sord[g * P_ + r];
    int gi = g * P_ + p;
    for (int q = 0; q < 4; ++q) {
      spx[r][q] = pts8[gi * 8 + q];
      spy[r][q] = pts8[gi * 8 + 4 + q];
    }
    sarea[r] = pr5[gi * 5 + 2] * pr5[gi * 5 + 3];
    if (scs[g * P_ + r] > 0.f) atomicAdd(&sV, 1);   // valid entries are a prefix
  }
  for (int w = tid; w < P_ * 8; w += 256) ((u64*)ssup)[w] = 0ull;
  __syncthreads();
  int V = sV;
  long long Tp = (long long)V * (V - 1) / 2;
  for (long long kk = tid; kk < Tp; kk += 256) {
    int i = (int)((1.0 + sqrt(1.0 + 8.0 * (double)kk)) * 0.5);
    while ((long long)i * (i - 1) / 2 > kk) --i;
    while ((long long)(i + 1) * i / 2 <= kk) ++i;
    int j = (int)(kk - (long long)i * (i - 1) / 2);
    // reference: iou[i][j] clips quad i by edges of quad j
    float inter = inter_area_dev(spx[i], spy[i], spx[j], spy[j]);
    float iou = inter / (((sarea[i] + sarea[j]) - inter) + 1e-8f);
    if (iou > NMS_THR) atomicOr(&ssup[i][j >> 6], 1ull << (j & 63));
  }
  __syncthreads();
  if (tid < 64) {   // wave 0: sequential greedy over bitmasks
    u64 keepw = 0;
    for (int i = 0; i < V; ++i) {
      u64 x = (tid < 8) ? (ssup[i][tid] & keepw) : 0ull;
      bool sup = __any(x != 0ull);
      if (!sup && tid == (i >> 6)) keepw |= 1ull << (i & 63);
    }
    if (tid < 8) skeep[tid] = keepw;
  }
  __syncthreads();
  if (tid == 0) {
    int cnt = 0;
    int cls = g % CF;
    for (int r = 0; r < V && cnt < DET; ++r) {
      if ((skeep[r >> 6] >> (r & 63)) & 1ull) {
        float sv = scs[g * P_ + r];
        int flat = cls * P_ + r;
        cand[g * DET + cnt] = ((u64)f2o(sv) << 32) | (u32)(~(u32)flat);
        ++cnt;
      }
    }
    for (; cnt < DET; ++cnt) cand[g * DET + cnt] = 0ull;
  }
}

// ---------------------------------------------------------------------------
// K4: per-image top-100 over <=2000 candidates (bitonic 2048), gather + write
// out layout: bb[2,100,4] | rr[2,100,5] | sc[2,100] | lab[2,100]  (all f32)
// ---------------------------------------------------------------------------
__global__ void topk_kernel(const u64* __restrict__ cand, const int* __restrict__ sord,
                            const float* __restrict__ pr5, const float* __restrict__ bb4,
                            float* __restrict__ out) {
  int b = blockIdx.x;
  int tid = threadIdx.x;
  __shared__ u64 sk[2048];
  for (int i = tid; i < 2048; i += 256)
    sk[i] = (i < CF * DET) ? cand[b * CF * DET + i] : 0ull;
  __syncthreads();
  for (int k = 2; k <= 2048; k <<= 1) {
    for (int j = k >> 1; j > 0; j >>= 1) {
      for (int i = tid; i < 2048; i += 256) {
        int ixj = i ^ j;
        if (ixj > i) {
          bool desc = ((i & k) == 0);
          u64 a = sk[i], c = sk[ixj];
          bool sw = desc ? (a < c) : (a > c);
          if (sw) { sk[i] = c; sk[ixj] = a; }
        }
      }
      __syncthreads();
    }
  }
  if (tid < DET) {
    u64 key = sk[tid];
    float score = o2f((u32)(key >> 32));
    bool ok = score > 0.f;   // NaN (pad) -> false
    int o_bb = (b * DET + tid) * 4;
    int o_rr = B_ * DET * 4 + (b * DET + tid) * 5;
    int o_sc = B_ * DET * 9 + b * DET + tid;
    int o_lab = B_ * DET * 10 + b * DET + tid;
    if (ok) {
      int flat = (int)(~(u32)key);
      int cls = flat >> 9, r = flat & (P_ - 1);
      int p = sord[(b * CF + cls) * P_ + r];
      int gi = (b * CF + cls) * P_ + p;
      for (int q = 0; q < 4; ++q) out[o_bb + q] = bb4[gi * 4 + q];
      for (int q = 0; q < 5; ++q) out[o_rr + q] = pr5[gi * 5 + q];
      out[o_sc] = score;
      out[o_lab] = (float)(cls + 1);
    } else {
      for (int q = 0; q < 4; ++q) out[o_bb + q] = 0.f;
      for (int q = 0; q < 5; ++q) out[o_rr + q] = 0.f;
      out[o_sc] = 0.f;
      out[o_lab] = 0.f;
    }
  }
}

// ---------------------------------------------------------------------------
extern "C" void kernel_launch(void* const* d_in, const int* in_sizes, int n_in,
                              void* d_out, int out_size, void* d_ws, size_t ws_size,
                              hipStream_t stream) {
  const float* logits = (const float*)d_in[0];
  const float* breg   = (const float*)d_in[1];
  const float* rrects = (const float*)d_in[2];
  float* out = (float*)d_out;

  u64*   cand = (u64*)d_ws;                         // 4000 u64
  float* smsk = (float*)(cand + B_ * CF * DET);     // 20480 f
  float* scs  = smsk + B_ * CF * P_;                // 20480 f
  int*   sord = (int*)(scs + B_ * CF * P_);         // 20480 i
  float* pr5  = (float*)(sord + B_ * CF * P_);      // 102400 f
  float* bb4  = pr5 + B_ * CF * P_ * 5;             // 81920 f
  float* pts8 = bb4 + B_ * CF * P_ * 4;             // 163840 f

  int total = B_ * P_ * CF;
  decode_kernel<<<(total + 255) / 256, 256, 0, stream>>>(logits, breg, rrects,
                                                         smsk, pr5, bb4, pts8);
  sort_kernel<<<B_ * CF, 256, 0, stream>>>(smsk, scs, sord);
  nms_kernel<<<B_ * CF, 256, 0, stream>>>(scs, sord, pr5, pts8, cand);
  topk_kernel<<<B_, 256, 0, stream>>>(cand, sord, pr5, bb4, out);
}

// Round 2
// 337.205 us; speedup vs baseline: 2.2578x; 2.2578x over previous
//
#include <hip/hip_runtime.h>
#include <stdint.h>

#pragma clang fp contract(off)

#define B_ 2
#define P_ 512
#define C_ 21
#define CF 20            // foreground classes
#define DET 100
#define SCORE_THRESH 0.05f
#define NMS_THR 0.5f
#define BBOX_CLIP 4.135166556742356f   // log(1000/16)

typedef unsigned long long u64;
typedef unsigned int u32;

// order-preserving float<->uint mapping (ascending uint == ascending float)
__device__ __forceinline__ u32 f2o(float f) {
  u32 u = __float_as_uint(f);
  return (u & 0x80000000u) ? ~u : (u | 0x80000000u);
}
__device__ __forceinline__ float o2f(u32 o) {
  u32 u = (o & 0x80000000u) ? (o ^ 0x80000000u) : ~o;
  return __uint_as_float(u);
}

// ---------------------------------------------------------------------------
// K1: softmax score + rotated decode + corner pts + clipped AABB
// ---------------------------------------------------------------------------
__global__ void decode_kernel(const float* __restrict__ logits,
                              const float* __restrict__ breg,
                              const float* __restrict__ rrects,
                              float* __restrict__ smsk,   // [B*CF*P] masked score
                              float* __restrict__ pr5,    // [B*CF*P][5]
                              float* __restrict__ bb4,    // [B*CF*P][4]
                              float* __restrict__ pts8) { // [B*CF*P][8] x0..3,y0..3
  int idx = blockIdx.x * blockDim.x + threadIdx.x;
  if (idx >= B_ * P_ * CF) return;
  int n = idx / CF;
  int cf = idx % CF;
  int c = cf + 1;
  int b = n / P_, p = n % P_;

  const float* lg = logits + n * C_;
  float mx = lg[0];
  for (int k = 1; k < C_; ++k) mx = fmaxf(mx, lg[k]);
  float den = 0.f;
  for (int k = 0; k < C_; ++k) den += expf(lg[k] - mx);
  float sc = expf(lg[c] - mx) / den;

  const float* d = breg + n * (C_ * 5) + c * 5;
  float dx = d[0] / 10.0f, dy = d[1] / 10.0f;
  float dw = d[2] / 5.0f, dh = d[3] / 5.0f, da = d[4] / 3.0f;
  dw = fminf(dw, BBOX_CLIP);
  dh = fminf(dh, BBOX_CLIP);
  const float* an = rrects + n * 5;
  float xc = an[0], yc = an[1], w = an[2], h = an[3], a = an[4];
  float px = dx * w + xc;
  float py = dy * h + yc;
  float pw = expf(dw) * w;
  float ph = expf(dh) * h;
  float pa = da * 57.29577951308232f + a;   // 180/pi

  int gi = (b * CF + cf) * P_ + p;
  pr5[gi * 5 + 0] = px; pr5[gi * 5 + 1] = py;
  pr5[gi * 5 + 2] = pw; pr5[gi * 5 + 3] = ph; pr5[gi * 5 + 4] = pa;

  float t = pa * 0.017453292519943295f;     // pi/180
  float cs = cosf(t), sn = sinf(t);
  float hx = pw * 0.5f, hy = ph * 0.5f;
  float ox[4] = {-hx, hx, hx, -hx};
  float oy[4] = {-hy, -hy, hy, hy};
  float minx = 1e30f, miny = 1e30f, maxx = -1e30f, maxy = -1e30f;
  for (int q = 0; q < 4; ++q) {
    float x = px + cs * ox[q] - sn * oy[q];
    float y = py + sn * ox[q] + cs * oy[q];
    pts8[gi * 8 + q] = x;
    pts8[gi * 8 + 4 + q] = y;
    minx = fminf(minx, x); maxx = fmaxf(maxx, x);
    miny = fminf(miny, y); maxy = fmaxf(maxy, y);
  }
  bb4[gi * 4 + 0] = fminf(fmaxf(minx, 0.f), 1023.0f);
  bb4[gi * 4 + 1] = fminf(fmaxf(miny, 0.f), 799.0f);
  bb4[gi * 4 + 2] = fminf(fmaxf(maxx, 0.f), 1023.0f);
  bb4[gi * 4 + 3] = fminf(fmaxf(maxy, 0.f), 799.0f);

  bool valid = sc > SCORE_THRESH;
  smsk[gi] = valid ? sc : -1.0f;
}

// ---------------------------------------------------------------------------
// K2: per-(image,class) descending sort, stable tie->lower idx; count valid V
// ---------------------------------------------------------------------------
__global__ void sort_kernel(const float* __restrict__ smsk,
                            float* __restrict__ scs, int* __restrict__ sord,
                            int* __restrict__ gV) {
  int g = blockIdx.x;
  int tid = threadIdx.x;
  __shared__ u64 key[P_];
  __shared__ int cnt;
  if (tid == 0) cnt = 0;
  for (int i = tid; i < P_; i += 256) {
    float v = smsk[g * P_ + i];
    key[i] = ((u64)f2o(v) << 32) | (u32)(~(u32)i);
  }
  __syncthreads();
  for (int k = 2; k <= P_; k <<= 1) {
    for (int j = k >> 1; j > 0; j >>= 1) {
      for (int i = tid; i < P_; i += 256) {
        int ixj = i ^ j;
        if (ixj > i) {
          bool desc = ((i & k) == 0);
          u64 a = key[i], b = key[ixj];
          bool sw = desc ? (a < b) : (a > b);
          if (sw) { key[i] = b; key[ixj] = a; }
        }
      }
      __syncthreads();
    }
  }
  for (int i = tid; i < P_; i += 256) {
    u64 kk = key[i];
    float v = o2f((u32)(kk >> 32));
    scs[g * P_ + i] = v;
    sord[g * P_ + i] = (int)(~(u32)kk);
    if (v > 0.f) atomicAdd(&cnt, 1);
  }
  __syncthreads();
  if (tid == 0) gV[g] = cnt;
}

// ---------------------------------------------------------------------------
// exact convex quad-quad intersection area — fully register-resident.
// Dynamic appends/reads replaced by unrolled static-index selects; float ops
// and their order are identical to the reference (fp contract off).
// ---------------------------------------------------------------------------
__device__ __forceinline__ float inter_area_reg(const float qx[4], const float qy[4],
                                                const float rx[4], const float ry[4]) {
  float px_[8], py_[8];
  #pragma unroll
  for (int t = 0; t < 8; ++t) { px_[t] = (t < 4) ? qx[t] : 0.f; py_[t] = (t < 4) ? qy[t] : 0.f; }
  int n = 4;
  #pragma unroll
  for (int e = 0; e < 4; ++e) {
    float a0 = rx[e], a1 = ry[e];
    float b0 = rx[(e + 1) & 3], b1 = ry[(e + 1) & 3];
    float dx = b0 - a0, dy = b1 - a1;
    float ox_[8], oy_[8];
    #pragma unroll
    for (int t = 0; t < 8; ++t) { ox_[t] = 0.f; oy_[t] = 0.f; }
    float cr[8];
    #pragma unroll
    for (int t = 0; t < 8; ++t) cr[t] = dx * (py_[t] - a1) - dy * (px_[t] - a0);
    int m = 0;
    int nn = (n > 1) ? n : 1;
    #pragma unroll
    for (int t = 0; t < 8; ++t) {
      bool act = t < n;
      float sx = px_[t], sy = py_[t];
      // e = poly[(t+1) % nn]; for active t: t+1==nn -> 0 else t+1 (static)
      float ex, ey, ce;
      if (t == 7) { ex = px_[0]; ey = py_[0]; ce = cr[0]; }
      else {
        bool wrap = (t + 1 == nn);
        ex = wrap ? px_[0] : px_[t + 1];
        ey = wrap ? py_[0] : py_[t + 1];
        ce = wrap ? cr[0] : cr[t + 1];
      }
      float cs = cr[t];
      float denom = cs - ce;
      float dn = (fabsf(denom) > 1e-12f) ? denom : 1e-12f;
      float tt = cs / dn;
      float ipx = sx + tt * (ex - sx);
      float ipy = sy + tt * (ey - sy);
      bool s_in = cs >= 0.f, e_in = ce >= 0.f;
      bool app1 = act && (s_in != e_in);
      #pragma unroll
      for (int s2 = 0; s2 < 8; ++s2) {
        bool wr = app1 && (m == s2);
        ox_[s2] = wr ? ipx : ox_[s2];
        oy_[s2] = wr ? ipy : oy_[s2];
      }
      m += app1 ? 1 : 0;
      bool app2 = act && e_in;
      #pragma unroll
      for (int s2 = 0; s2 < 8; ++s2) {
        bool wr = app2 && (m == s2);
        ox_[s2] = wr ? ex : ox_[s2];
        oy_[s2] = wr ? ey : oy_[s2];
      }
      m += app2 ? 1 : 0;
    }
    n = m;
    #pragma unroll
    for (int t = 0; t < 8; ++t) { px_[t] = ox_[t]; py_[t] = oy_[t]; }
  }
  int nn = (n > 1) ? n : 1;
  float s = 0.f;
  #pragma unroll
  for (int t = 0; t < 8; ++t) {
    if (t < n) {
      float nx_x, nx_y;
      if (t == 7) { nx_x = px_[0]; nx_y = py_[0]; }
      else {
        bool wrap = (t + 1 == nn);
        nx_x = wrap ? px_[0] : px_[t + 1];
        nx_y = wrap ? py_[0] : py_[t + 1];
      }
      s += px_[t] * nx_y - nx_x * py_[t];
    }
  }
  float area = 0.5f * fabsf(s);
  return (n >= 3) ? area : 0.f;
}

// ---------------------------------------------------------------------------
// K3a: suppression bitmatrix over all (i>j) valid pairs, grid-parallel.
// grid = (64, 40); 256 thr x 8 pairs = 2048 pairs/block.
// ---------------------------------------------------------------------------
#define PPT 8
#define TPB 256
__global__ void pair_kernel(const int* __restrict__ sord, const int* __restrict__ gV,
                            const float* __restrict__ pr5, const float* __restrict__ pts8,
                            u64* __restrict__ sup) {
  int g = blockIdx.y;
  int V = gV[g];
  long long Tp = (long long)V * (V - 1) / 2;
  long long base = (long long)blockIdx.x * (TPB * PPT);
  if (base >= Tp) return;
  int tid = threadIdx.x;
  long long k0 = base + (long long)tid * PPT;
  for (int q = 0; q < PPT; ++q) {
    long long kk = k0 + q;
    if (kk >= Tp) break;
    int i = (int)((1.0 + sqrt(1.0 + 8.0 * (double)kk)) * 0.5);
    while ((long long)i * (i - 1) / 2 > kk) --i;
    while ((long long)(i + 1) * i / 2 <= kk) ++i;
    int j = (int)(kk - (long long)i * (i - 1) / 2);
    int io = sord[g * P_ + i];
    int jo = sord[g * P_ + j];
    const float* Pi = pts8 + (size_t)(g * P_ + io) * 8;
    const float* Pj = pts8 + (size_t)(g * P_ + jo) * 8;
    float qx[4], qy[4], rx[4], ry[4];
    #pragma unroll
    for (int t = 0; t < 4; ++t) {
      qx[t] = Pi[t]; qy[t] = Pi[4 + t];
      rx[t] = Pj[t]; ry[t] = Pj[4 + t];
    }
    float ai = pr5[(size_t)(g * P_ + io) * 5 + 2] * pr5[(size_t)(g * P_ + io) * 5 + 3];
    float aj = pr5[(size_t)(g * P_ + jo) * 5 + 2] * pr5[(size_t)(g * P_ + jo) * 5 + 3];
    // reference iou[i][j]: clip quad i by edges of quad j
    float inter = inter_area_reg(qx, qy, rx, ry);
    float iou = inter / (((ai + aj) - inter) + 1e-8f);
    if (iou > NMS_THR)
      atomicOr(&sup[((size_t)g * P_ + i) * 8 + (j >> 6)], 1ull << (j & 63));
  }
}

// ---------------------------------------------------------------------------
// K3b: sequential greedy over bitmasks + emit first 100 kept per group
// ---------------------------------------------------------------------------
__global__ void greedy_kernel(const float* __restrict__ scs, const int* __restrict__ gV,
                              const u64* __restrict__ sup, u64* __restrict__ cand) {
  int g = blockIdx.x;
  int tid = threadIdx.x;   // 64
  __shared__ u64 lsup[P_ * 8];
  __shared__ u64 skeep[8];
  int V = gV[g];
  for (int w = tid; w < V * 8; w += 64) lsup[w] = sup[(size_t)g * P_ * 8 + w];
  __syncthreads();
  u64 keepw = 0;
  for (int i = 0; i < V; ++i) {
    u64 x = (tid < 8) ? (lsup[i * 8 + tid] & keepw) : 0ull;
    bool supd = __any(x != 0ull);
    if (!supd && tid == (i >> 6)) keepw |= 1ull << (i & 63);
  }
  if (tid < 8) skeep[tid] = keepw;
  __syncthreads();
  if (tid == 0) {
    int cnt = 0, cls = g % CF;
    for (int r = 0; r < V && cnt < DET; ++r) {
      if ((skeep[r >> 6] >> (r & 63)) & 1ull) {
        float sv = scs[g * P_ + r];
        int flat = cls * P_ + r;
        cand[g * DET + cnt] = ((u64)f2o(sv) << 32) | (u32)(~(u32)flat);
        ++cnt;
      }
    }
    for (; cnt < DET; ++cnt) cand[g * DET + cnt] = 0ull;
  }
}

// ---------------------------------------------------------------------------
// K4: per-image top-100 over <=2000 candidates (bitonic 2048), gather + write
// out layout: bb[2,100,4] | rr[2,100,5] | sc[2,100] | lab[2,100]  (all f32)
// ---------------------------------------------------------------------------
__global__ void topk_kernel(const u64* __restrict__ cand, const int* __restrict__ sord,
                            const float* __restrict__ pr5, const float* __restrict__ bb4,
                            float* __restrict__ out) {
  int b = blockIdx.x;
  int tid = threadIdx.x;
  __shared__ u64 sk[2048];
  for (int i = tid; i < 2048; i += 256)
    sk[i] = (i < CF * DET) ? cand[b * CF * DET + i] : 0ull;
  __syncthreads();
  for (int k = 2; k <= 2048; k <<= 1) {
    for (int j = k >> 1; j > 0; j >>= 1) {
      for (int i = tid; i < 2048; i += 256) {
        int ixj = i ^ j;
        if (ixj > i) {
          bool desc = ((i & k) == 0);
          u64 a = sk[i], c = sk[ixj];
          bool sw = desc ? (a < c) : (a > c);
          if (sw) { sk[i] = c; sk[ixj] = a; }
        }
      }
      __syncthreads();
    }
  }
  if (tid < DET) {
    u64 key = sk[tid];
    float score = o2f((u32)(key >> 32));
    bool ok = score > 0.f;   // NaN (pad) -> false
    int o_bb = (b * DET + tid) * 4;
    int o_rr = B_ * DET * 4 + (b * DET + tid) * 5;
    int o_sc = B_ * DET * 9 + b * DET + tid;
    int o_lab = B_ * DET * 10 + b * DET + tid;
    if (ok) {
      int flat = (int)(~(u32)key);
      int cls = flat >> 9, r = flat & (P_ - 1);
      int p = sord[(b * CF + cls) * P_ + r];
      int gi = (b * CF + cls) * P_ + p;
      for (int q = 0; q < 4; ++q) out[o_bb + q] = bb4[gi * 4 + q];
      for (int q = 0; q < 5; ++q) out[o_rr + q] = pr5[gi * 5 + q];
      out[o_sc] = score;
      out[o_lab] = (float)(cls + 1);
    } else {
      for (int q = 0; q < 4; ++q) out[o_bb + q] = 0.f;
      for (int q = 0; q < 5; ++q) out[o_rr + q] = 0.f;
      out[o_sc] = 0.f;
      out[o_lab] = 0.f;
    }
  }
}

// ---------------------------------------------------------------------------
extern "C" void kernel_launch(void* const* d_in, const int* in_sizes, int n_in,
                              void* d_out, int out_size, void* d_ws, size_t ws_size,
                              hipStream_t stream) {
  const float* logits = (const float*)d_in[0];
  const float* breg   = (const float*)d_in[1];
  const float* rrects = (const float*)d_in[2];
  float* out = (float*)d_out;

  u64*   sup  = (u64*)d_ws;                         // 40*512*8 u64 = 1.25 MB
  u64*   cand = sup + (size_t)B_ * CF * P_ * 8;     // 4000 u64
  int*   gV   = (int*)(cand + B_ * CF * DET);       // 40 (+pad)
  float* smsk = (float*)(gV + 64);                  // 20480 f
  float* scs  = smsk + B_ * CF * P_;                // 20480 f
  int*   sord = (int*)(scs + B_ * CF * P_);         // 20480 i
  float* pr5  = (float*)(sord + B_ * CF * P_);      // 102400 f
  float* bb4  = pr5 + (size_t)B_ * CF * P_ * 5;     // 81920 f
  float* pts8 = bb4 + (size_t)B_ * CF * P_ * 4;     // 163840 f

  hipMemsetAsync(sup, 0, (size_t)B_ * CF * P_ * 8 * sizeof(u64), stream);

  int total = B_ * P_ * CF;
  decode_kernel<<<(total + 255) / 256, 256, 0, stream>>>(logits, breg, rrects,
                                                         smsk, pr5, bb4, pts8);
  sort_kernel<<<B_ * CF, 256, 0, stream>>>(smsk, scs, sord, gV);
  pair_kernel<<<dim3(64, B_ * CF), TPB, 0, stream>>>(sord, gV, pr5, pts8, sup);
  greedy_kernel<<<B_ * CF, 64, 0, stream>>>(scs, gV, sup, cand);
  topk_kernel<<<B_, 256, 0, stream>>>(cand, sord, pr5, bb4, out);
}

// Round 3
// 210.313 us; speedup vs baseline: 3.6201x; 1.6034x over previous
//
#include <hip/hip_runtime.h>
#include <stdint.h>

#pragma clang fp contract(off)

#define B_ 2
#define P_ 512
#define C_ 21
#define CF 20            // foreground classes
#define DET 100
#define SCORE_THRESH 0.05f
#define NMS_THR 0.5f
#define BBOX_CLIP 4.135166556742356f   // log(1000/16)

typedef unsigned long long u64;
typedef unsigned int u32;

// order-preserving float<->uint mapping (ascending uint == ascending float)
__device__ __forceinline__ u32 f2o(float f) {
  u32 u = __float_as_uint(f);
  return (u & 0x80000000u) ? ~u : (u | 0x80000000u);
}
__device__ __forceinline__ float o2f(u32 o) {
  u32 u = (o & 0x80000000u) ? (o ^ 0x80000000u) : ~o;
  return __uint_as_float(u);
}

// ---------------------------------------------------------------------------
// K1: softmax score + rotated decode + corner pts + clipped AABB
// ---------------------------------------------------------------------------
__global__ void decode_kernel(const float* __restrict__ logits,
                              const float* __restrict__ breg,
                              const float* __restrict__ rrects,
                              float* __restrict__ smsk,   // [B*CF*P] masked score
                              float* __restrict__ pr5,    // [B*CF*P][5]
                              float* __restrict__ bb4,    // [B*CF*P][4]
                              float* __restrict__ pts8) { // [B*CF*P][8] x0..3,y0..3
  int idx = blockIdx.x * blockDim.x + threadIdx.x;
  if (idx >= B_ * P_ * CF) return;
  int n = idx / CF;
  int cf = idx % CF;
  int c = cf + 1;
  int b = n / P_, p = n % P_;

  const float* lg = logits + n * C_;
  float mx = lg[0];
  for (int k = 1; k < C_; ++k) mx = fmaxf(mx, lg[k]);
  float den = 0.f;
  for (int k = 0; k < C_; ++k) den += expf(lg[k] - mx);
  float sc = expf(lg[c] - mx) / den;

  const float* d = breg + n * (C_ * 5) + c * 5;
  float dx = d[0] / 10.0f, dy = d[1] / 10.0f;
  float dw = d[2] / 5.0f, dh = d[3] / 5.0f, da = d[4] / 3.0f;
  dw = fminf(dw, BBOX_CLIP);
  dh = fminf(dh, BBOX_CLIP);
  const float* an = rrects + n * 5;
  float xc = an[0], yc = an[1], w = an[2], h = an[3], a = an[4];
  float px = dx * w + xc;
  float py = dy * h + yc;
  float pw = expf(dw) * w;
  float ph = expf(dh) * h;
  float pa = da * 57.29577951308232f + a;   // 180/pi

  int gi = (b * CF + cf) * P_ + p;
  pr5[gi * 5 + 0] = px; pr5[gi * 5 + 1] = py;
  pr5[gi * 5 + 2] = pw; pr5[gi * 5 + 3] = ph; pr5[gi * 5 + 4] = pa;

  float t = pa * 0.017453292519943295f;     // pi/180
  float cs = cosf(t), sn = sinf(t);
  float hx = pw * 0.5f, hy = ph * 0.5f;
  float ox[4] = {-hx, hx, hx, -hx};
  float oy[4] = {-hy, -hy, hy, hy};
  float minx = 1e30f, miny = 1e30f, maxx = -1e30f, maxy = -1e30f;
  for (int q = 0; q < 4; ++q) {
    float x = px + cs * ox[q] - sn * oy[q];
    float y = py + sn * ox[q] + cs * oy[q];
    pts8[gi * 8 + q] = x;
    pts8[gi * 8 + 4 + q] = y;
    minx = fminf(minx, x); maxx = fmaxf(maxx, x);
    miny = fminf(miny, y); maxy = fmaxf(maxy, y);
  }
  bb4[gi * 4 + 0] = fminf(fmaxf(minx, 0.f), 1023.0f);
  bb4[gi * 4 + 1] = fminf(fmaxf(miny, 0.f), 799.0f);
  bb4[gi * 4 + 2] = fminf(fmaxf(maxx, 0.f), 1023.0f);
  bb4[gi * 4 + 3] = fminf(fmaxf(maxy, 0.f), 799.0f);

  bool valid = sc > SCORE_THRESH;
  smsk[gi] = valid ? sc : -1.0f;
}

// ---------------------------------------------------------------------------
// K2: per-(image,class) descending sort, stable tie->lower idx; count valid V;
// emit sorted-order pts / unclipped AABB / area; zero this group's sup slice.
// ---------------------------------------------------------------------------
__global__ void sort_kernel(const float* __restrict__ smsk,
                            const float* __restrict__ pts8,
                            const float* __restrict__ pr5,
                            float* __restrict__ scs, int* __restrict__ sord,
                            int* __restrict__ gV,
                            float* __restrict__ ptsS,    // [G*P][8] sorted pts
                            float* __restrict__ aabbA,   // [G*P][4] sorted unclipped aabb
                            float* __restrict__ areaA,   // [G*P] sorted area
                            u64* __restrict__ sup) {
  int g = blockIdx.x;
  int tid = threadIdx.x;
  __shared__ u64 key[P_];
  __shared__ int cnt;
  if (tid == 0) cnt = 0;
  for (int i = tid; i < P_; i += 256) {
    float v = smsk[g * P_ + i];
    key[i] = ((u64)f2o(v) << 32) | (u32)(~(u32)i);
  }
  // zero suppression matrix slice while sort waits anyway
  for (int w = tid; w < P_ * 8; w += 256) sup[(size_t)g * P_ * 8 + w] = 0ull;
  __syncthreads();
  for (int k = 2; k <= P_; k <<= 1) {
    for (int j = k >> 1; j > 0; j >>= 1) {
      for (int i = tid; i < P_; i += 256) {
        int ixj = i ^ j;
        if (ixj > i) {
          bool desc = ((i & k) == 0);
          u64 a = key[i], b = key[ixj];
          bool sw = desc ? (a < b) : (a > b);
          if (sw) { key[i] = b; key[ixj] = a; }
        }
      }
      __syncthreads();
    }
  }
  for (int i = tid; i < P_; i += 256) {
    u64 kk = key[i];
    float v = o2f((u32)(kk >> 32));
    int p = (int)(~(u32)kk);
    scs[g * P_ + i] = v;
    sord[g * P_ + i] = p;
    if (v > 0.f) atomicAdd(&cnt, 1);
    int gi = g * P_ + p;
    float4 xs = ((const float4*)pts8)[gi * 2];
    float4 ys = ((const float4*)pts8)[gi * 2 + 1];
    int so = g * P_ + i;
    ((float4*)ptsS)[so * 2] = xs;
    ((float4*)ptsS)[so * 2 + 1] = ys;
    float mnx = fminf(fminf(xs.x, xs.y), fminf(xs.z, xs.w));
    float mxx = fmaxf(fmaxf(xs.x, xs.y), fmaxf(xs.z, xs.w));
    float mny = fminf(fminf(ys.x, ys.y), fminf(ys.z, ys.w));
    float mxy = fmaxf(fmaxf(ys.x, ys.y), fmaxf(ys.z, ys.w));
    ((float4*)aabbA)[so] = make_float4(mnx, mny, mxx, mxy);
    areaA[so] = pr5[gi * 5 + 2] * pr5[gi * 5 + 3];
  }
  __syncthreads();
  if (tid == 0) gV[g] = cnt;
}

// ---------------------------------------------------------------------------
// exact convex quad-quad intersection area — register-resident, bit-identical
// float op order vs reference (fp contract off)
// ---------------------------------------------------------------------------
__device__ __forceinline__ float inter_area_reg(const float qx[4], const float qy[4],
                                                const float rx[4], const float ry[4]) {
  float px_[8], py_[8];
  #pragma unroll
  for (int t = 0; t < 8; ++t) { px_[t] = (t < 4) ? qx[t] : 0.f; py_[t] = (t < 4) ? qy[t] : 0.f; }
  int n = 4;
  #pragma unroll
  for (int e = 0; e < 4; ++e) {
    float a0 = rx[e], a1 = ry[e];
    float b0 = rx[(e + 1) & 3], b1 = ry[(e + 1) & 3];
    float dx = b0 - a0, dy = b1 - a1;
    float ox_[8], oy_[8];
    #pragma unroll
    for (int t = 0; t < 8; ++t) { ox_[t] = 0.f; oy_[t] = 0.f; }
    float cr[8];
    #pragma unroll
    for (int t = 0; t < 8; ++t) cr[t] = dx * (py_[t] - a1) - dy * (px_[t] - a0);
    int m = 0;
    int nn = (n > 1) ? n : 1;
    #pragma unroll
    for (int t = 0; t < 8; ++t) {
      bool act = t < n;
      float sx = px_[t], sy = py_[t];
      float ex, ey, ce;
      if (t == 7) { ex = px_[0]; ey = py_[0]; ce = cr[0]; }
      else {
        bool wrap = (t + 1 == nn);
        ex = wrap ? px_[0] : px_[t + 1];
        ey = wrap ? py_[0] : py_[t + 1];
        ce = wrap ? cr[0] : cr[t + 1];
      }
      float cs = cr[t];
      float denom = cs - ce;
      float dn = (fabsf(denom) > 1e-12f) ? denom : 1e-12f;
      float tt = cs / dn;
      float ipx = sx + tt * (ex - sx);
      float ipy = sy + tt * (ey - sy);
      bool s_in = cs >= 0.f, e_in = ce >= 0.f;
      bool app1 = act && (s_in != e_in);
      #pragma unroll
      for (int s2 = 0; s2 < 8; ++s2) {
        bool wr = app1 && (m == s2);
        ox_[s2] = wr ? ipx : ox_[s2];
        oy_[s2] = wr ? ipy : oy_[s2];
      }
      m += app1 ? 1 : 0;
      bool app2 = act && e_in;
      #pragma unroll
      for (int s2 = 0; s2 < 8; ++s2) {
        bool wr = app2 && (m == s2);
        ox_[s2] = wr ? ex : ox_[s2];
        oy_[s2] = wr ? ey : oy_[s2];
      }
      m += app2 ? 1 : 0;
    }
    n = m;
    #pragma unroll
    for (int t = 0; t < 8; ++t) { px_[t] = ox_[t]; py_[t] = oy_[t]; }
  }
  int nn = (n > 1) ? n : 1;
  float s = 0.f;
  #pragma unroll
  for (int t = 0; t < 8; ++t) {
    if (t < n) {
      float nx_x, nx_y;
      if (t == 7) { nx_x = px_[0]; nx_y = py_[0]; }
      else {
        bool wrap = (t + 1 == nn);
        nx_x = wrap ? px_[0] : px_[t + 1];
        nx_y = wrap ? py_[0] : py_[t + 1];
      }
      s += px_[t] * nx_y - nx_x * py_[t];
    }
  }
  float area = 0.5f * fabsf(s);
  return (n >= 3) ? area : 0.f;
}

// ---------------------------------------------------------------------------
// K3a: AABB-filter + LDS-compact + dense IoU over surviving pairs.
// grid = (128, 40); 256 thr x 4 pair-slots = 1024 pairs/block.
// ---------------------------------------------------------------------------
#define PPT 4
#define TPB 256
__global__ void pair_kernel(const int* __restrict__ gV,
                            const float* __restrict__ aabbA,
                            const float* __restrict__ areaA,
                            const float* __restrict__ ptsS,
                            u64* __restrict__ sup) {
  int g = blockIdx.y;
  int V = gV[g];
  long long Tp = (long long)V * (V - 1) / 2;
  long long base = (long long)blockIdx.x * (TPB * PPT);
  if (base >= Tp) return;
  __shared__ u32 q[TPB * PPT];
  __shared__ int qn;
  int tid = threadIdx.x;
  if (tid == 0) qn = 0;
  __syncthreads();
  const float4* ab = (const float4*)aabbA;
  for (int t = 0; t < PPT; ++t) {
    long long kk = base + t * TPB + tid;     // coalesced within wave
    if (kk >= Tp) break;
    float kf = (float)kk;
    int i = (int)((1.0f + sqrtf(1.0f + 8.0f * kf)) * 0.5f);
    while ((long long)i * (i - 1) / 2 > kk) --i;
    while ((long long)(i + 1) * i / 2 <= kk) ++i;
    int j = (int)(kk - (long long)i * (i - 1) / 2);
    float4 bi = ab[g * P_ + i];
    float4 bj = ab[g * P_ + j];
    // non-strict overlap: reject only when strictly separated
    bool ov = (bi.x <= bj.z) && (bj.x <= bi.z) && (bi.y <= bj.w) && (bj.y <= bi.w);
    if (ov) {
      int s = atomicAdd(&qn, 1);
      q[s] = (u32)((i << 9) | j);
    }
  }
  __syncthreads();
  int nq = qn;
  const float4* pS = (const float4*)ptsS;
  for (int s = tid; s < nq; s += TPB) {
    u32 pk = q[s];
    int i = (int)(pk >> 9), j = (int)(pk & 511);
    float4 ax = pS[(g * P_ + i) * 2];
    float4 ay = pS[(g * P_ + i) * 2 + 1];
    float4 bx = pS[(g * P_ + j) * 2];
    float4 by = pS[(g * P_ + j) * 2 + 1];
    float qx[4] = {ax.x, ax.y, ax.z, ax.w};
    float qy[4] = {ay.x, ay.y, ay.z, ay.w};
    float rx[4] = {bx.x, bx.y, bx.z, bx.w};
    float ry[4] = {by.x, by.y, by.z, by.w};
    float ai = areaA[g * P_ + i];
    float aj = areaA[g * P_ + j];
    // reference iou[i][j]: clip quad i by edges of quad j
    float inter = inter_area_reg(qx, qy, rx, ry);
    float iou = inter / (((ai + aj) - inter) + 1e-8f);
    if (iou > NMS_THR)
      atomicOr(&sup[((size_t)g * P_ + i) * 8 + (j >> 6)], 1ull << (j & 63));
  }
}

// ---------------------------------------------------------------------------
// K3b: sequential greedy over bitmasks + emit first 100 kept per group
// ---------------------------------------------------------------------------
__global__ void greedy_kernel(const float* __restrict__ scs, const int* __restrict__ gV,
                              const u64* __restrict__ sup, u64* __restrict__ cand) {
  int g = blockIdx.x;
  int tid = threadIdx.x;   // 64
  __shared__ u64 lsup[P_ * 8];
  __shared__ u64 skeep[8];
  int V = gV[g];
  for (int w = tid; w < V * 8; w += 64) lsup[w] = sup[(size_t)g * P_ * 8 + w];
  __syncthreads();
  u64 keepw = 0;
  for (int i = 0; i < V; ++i) {
    u64 x = (tid < 8) ? (lsup[i * 8 + tid] & keepw) : 0ull;
    bool supd = __any(x != 0ull);
    if (!supd && tid == (i >> 6)) keepw |= 1ull << (i & 63);
  }
  if (tid < 8) skeep[tid] = keepw;
  __syncthreads();
  if (tid == 0) {
    int cnt = 0, cls = g % CF;
    for (int r = 0; r < V && cnt < DET; ++r) {
      if ((skeep[r >> 6] >> (r & 63)) & 1ull) {
        float sv = scs[g * P_ + r];
        int flat = cls * P_ + r;
        cand[g * DET + cnt] = ((u64)f2o(sv) << 32) | (u32)(~(u32)flat);
        ++cnt;
      }
    }
    for (; cnt < DET; ++cnt) cand[g * DET + cnt] = 0ull;
  }
}

// ---------------------------------------------------------------------------
// K4: per-image top-100 over <=2000 candidates (bitonic 2048), gather + write
// out layout: bb[2,100,4] | rr[2,100,5] | sc[2,100] | lab[2,100]  (all f32)
// ---------------------------------------------------------------------------
__global__ void topk_kernel(const u64* __restrict__ cand, const int* __restrict__ sord,
                            const float* __restrict__ pr5, const float* __restrict__ bb4,
                            float* __restrict__ out) {
  int b = blockIdx.x;
  int tid = threadIdx.x;
  __shared__ u64 sk[2048];
  for (int i = tid; i < 2048; i += 256)
    sk[i] = (i < CF * DET) ? cand[b * CF * DET + i] : 0ull;
  __syncthreads();
  for (int k = 2; k <= 2048; k <<= 1) {
    for (int j = k >> 1; j > 0; j >>= 1) {
      for (int i = tid; i < 2048; i += 256) {
        int ixj = i ^ j;
        if (ixj > i) {
          bool desc = ((i & k) == 0);
          u64 a = sk[i], c = sk[ixj];
          bool sw = desc ? (a < c) : (a > c);
          if (sw) { sk[i] = c; sk[ixj] = a; }
        }
      }
      __syncthreads();
    }
  }
  if (tid < DET) {
    u64 key = sk[tid];
    float score = o2f((u32)(key >> 32));
    bool ok = score > 0.f;
    int o_bb = (b * DET + tid) * 4;
    int o_rr = B_ * DET * 4 + (b * DET + tid) * 5;
    int o_sc = B_ * DET * 9 + b * DET + tid;
    int o_lab = B_ * DET * 10 + b * DET + tid;
    if (ok) {
      int flat = (int)(~(u32)key);
      int cls = flat >> 9, r = flat & (P_ - 1);
      int p = sord[(b * CF + cls) * P_ + r];
      int gi = (b * CF + cls) * P_ + p;
      for (int q = 0; q < 4; ++q) out[o_bb + q] = bb4[gi * 4 + q];
      for (int q = 0; q < 5; ++q) out[o_rr + q] = pr5[gi * 5 + q];
      out[o_sc] = score;
      out[o_lab] = (float)(cls + 1);
    } else {
      for (int q = 0; q < 4; ++q) out[o_bb + q] = 0.f;
      for (int q = 0; q < 5; ++q) out[o_rr + q] = 0.f;
      out[o_sc] = 0.f;
      out[o_lab] = 0.f;
    }
  }
}

// ---------------------------------------------------------------------------
extern "C" void kernel_launch(void* const* d_in, const int* in_sizes, int n_in,
                              void* d_out, int out_size, void* d_ws, size_t ws_size,
                              hipStream_t stream) {
  const float* logits = (const float*)d_in[0];
  const float* breg   = (const float*)d_in[1];
  const float* rrects = (const float*)d_in[2];
  float* out = (float*)d_out;

  const int G = B_ * CF;
  u64*   sup  = (u64*)d_ws;                          // G*512*8 u64 = 1.31 MB
  u64*   cand = sup + (size_t)G * P_ * 8;            // 4000 u64
  int*   gV   = (int*)(cand + G * DET);              // 64 ints (padded)
  float* smsk = (float*)(gV + 64);
  float* scs  = smsk + G * P_;
  int*   sord = (int*)(scs + G * P_);
  float* pr5  = (float*)(sord + G * P_);
  float* bb4  = pr5 + (size_t)G * P_ * 5;
  float* pts8 = bb4 + (size_t)G * P_ * 4;
  float* ptsS = pts8 + (size_t)G * P_ * 8;
  float* aabbA = ptsS + (size_t)G * P_ * 8;
  float* areaA = aabbA + (size_t)G * P_ * 4;

  int total = B_ * P_ * CF;
  decode_kernel<<<(total + 255) / 256, 256, 0, stream>>>(logits, breg, rrects,
                                                         smsk, pr5, bb4, pts8);
  sort_kernel<<<G, 256, 0, stream>>>(smsk, pts8, pr5, scs, sord, gV,
                                     ptsS, aabbA, areaA, sup);
  pair_kernel<<<dim3(128, G), TPB, 0, stream>>>(gV, aabbA, areaA, ptsS, sup);
  greedy_kernel<<<G, 64, 0, stream>>>(scs, gV, sup, cand);
  topk_kernel<<<B_, 256, 0, stream>>>(cand, sord, pr5, bb4, out);
}

// Round 4
// 162.345 us; speedup vs baseline: 4.6897x; 1.2955x over previous
//
#include <hip/hip_runtime.h>
#include <stdint.h>

#pragma clang fp contract(off)

#define B_ 2
#define P_ 512
#define C_ 21
#define CF 20            // foreground classes
#define DET 100
#define SCORE_THRESH 0.05f
#define NMS_THR 0.5f
#define BBOX_CLIP 4.135166556742356f   // log(1000/16)

typedef unsigned long long u64;
typedef unsigned int u32;

// order-preserving float<->uint mapping (ascending uint == ascending float)
__device__ __forceinline__ u32 f2o(float f) {
  u32 u = __float_as_uint(f);
  return (u & 0x80000000u) ? ~u : (u | 0x80000000u);
}
__device__ __forceinline__ float o2f(u32 o) {
  u32 u = (o & 0x80000000u) ? (o ^ 0x80000000u) : ~o;
  return __uint_as_float(u);
}

// ---------------------------------------------------------------------------
// K1: softmax score + rotated decode + corner pts + clipped AABB
// ---------------------------------------------------------------------------
__global__ void decode_kernel(const float* __restrict__ logits,
                              const float* __restrict__ breg,
                              const float* __restrict__ rrects,
                              float* __restrict__ smsk,   // [B*CF*P] masked score
                              float* __restrict__ pr5,    // [B*CF*P][5]
                              float* __restrict__ bb4,    // [B*CF*P][4]
                              float* __restrict__ pts8) { // [B*CF*P][8] x0..3,y0..3
  int idx = blockIdx.x * blockDim.x + threadIdx.x;
  if (idx >= B_ * P_ * CF) return;
  int n = idx / CF;
  int cf = idx % CF;
  int c = cf + 1;
  int b = n / P_, p = n % P_;

  const float* lg = logits + n * C_;
  float mx = lg[0];
  for (int k = 1; k < C_; ++k) mx = fmaxf(mx, lg[k]);
  float den = 0.f;
  for (int k = 0; k < C_; ++k) den += expf(lg[k] - mx);
  float sc = expf(lg[c] - mx) / den;

  const float* d = breg + n * (C_ * 5) + c * 5;
  float dx = d[0] / 10.0f, dy = d[1] / 10.0f;
  float dw = d[2] / 5.0f, dh = d[3] / 5.0f, da = d[4] / 3.0f;
  dw = fminf(dw, BBOX_CLIP);
  dh = fminf(dh, BBOX_CLIP);
  const float* an = rrects + n * 5;
  float xc = an[0], yc = an[1], w = an[2], h = an[3], a = an[4];
  float px = dx * w + xc;
  float py = dy * h + yc;
  float pw = expf(dw) * w;
  float ph = expf(dh) * h;
  float pa = da * 57.29577951308232f + a;   // 180/pi

  int gi = (b * CF + cf) * P_ + p;
  pr5[gi * 5 + 0] = px; pr5[gi * 5 + 1] = py;
  pr5[gi * 5 + 2] = pw; pr5[gi * 5 + 3] = ph; pr5[gi * 5 + 4] = pa;

  float t = pa * 0.017453292519943295f;     // pi/180
  float cs = cosf(t), sn = sinf(t);
  float hx = pw * 0.5f, hy = ph * 0.5f;
  float ox[4] = {-hx, hx, hx, -hx};
  float oy[4] = {-hy, -hy, hy, hy};
  float minx = 1e30f, miny = 1e30f, maxx = -1e30f, maxy = -1e30f;
  for (int q = 0; q < 4; ++q) {
    float x = px + cs * ox[q] - sn * oy[q];
    float y = py + sn * ox[q] + cs * oy[q];
    pts8[gi * 8 + q] = x;
    pts8[gi * 8 + 4 + q] = y;
    minx = fminf(minx, x); maxx = fmaxf(maxx, x);
    miny = fminf(miny, y); maxy = fmaxf(maxy, y);
  }
  bb4[gi * 4 + 0] = fminf(fmaxf(minx, 0.f), 1023.0f);
  bb4[gi * 4 + 1] = fminf(fmaxf(miny, 0.f), 799.0f);
  bb4[gi * 4 + 2] = fminf(fmaxf(maxx, 0.f), 1023.0f);
  bb4[gi * 4 + 3] = fminf(fmaxf(maxy, 0.f), 799.0f);

  bool valid = sc > SCORE_THRESH;
  smsk[gi] = valid ? sc : -1.0f;
}

// ---------------------------------------------------------------------------
// K2: per-(image,class) descending sort, stable tie->lower idx; count valid V;
// emit sorted-order pts / unclipped AABB / area; zero this group's sup slice.
// ---------------------------------------------------------------------------
__global__ void sort_kernel(const float* __restrict__ smsk,
                            const float* __restrict__ pts8,
                            const float* __restrict__ pr5,
                            float* __restrict__ scs, int* __restrict__ sord,
                            int* __restrict__ gV,
                            float* __restrict__ ptsS,    // [G*P][8] sorted pts
                            float* __restrict__ aabbA,   // [G*P][4] sorted unclipped aabb
                            float* __restrict__ areaA,   // [G*P] sorted area
                            u64* __restrict__ sup) {
  int g = blockIdx.x;
  int tid = threadIdx.x;
  __shared__ u64 key[P_];
  __shared__ int cnt;
  if (tid == 0) cnt = 0;
  for (int i = tid; i < P_; i += 256) {
    float v = smsk[g * P_ + i];
    key[i] = ((u64)f2o(v) << 32) | (u32)(~(u32)i);
  }
  // zero suppression matrix slice while sort waits anyway
  for (int w = tid; w < P_ * 8; w += 256) sup[(size_t)g * P_ * 8 + w] = 0ull;
  __syncthreads();
  for (int k = 2; k <= P_; k <<= 1) {
    for (int j = k >> 1; j > 0; j >>= 1) {
      for (int i = tid; i < P_; i += 256) {
        int ixj = i ^ j;
        if (ixj > i) {
          bool desc = ((i & k) == 0);
          u64 a = key[i], b = key[ixj];
          bool sw = desc ? (a < b) : (a > b);
          if (sw) { key[i] = b; key[ixj] = a; }
        }
      }
      __syncthreads();
    }
  }
  for (int i = tid; i < P_; i += 256) {
    u64 kk = key[i];
    float v = o2f((u32)(kk >> 32));
    int p = (int)(~(u32)kk);
    scs[g * P_ + i] = v;
    sord[g * P_ + i] = p;
    if (v > 0.f) atomicAdd(&cnt, 1);
    int gi = g * P_ + p;
    float4 xs = ((const float4*)pts8)[gi * 2];
    float4 ys = ((const float4*)pts8)[gi * 2 + 1];
    int so = g * P_ + i;
    ((float4*)ptsS)[so * 2] = xs;
    ((float4*)ptsS)[so * 2 + 1] = ys;
    float mnx = fminf(fminf(xs.x, xs.y), fminf(xs.z, xs.w));
    float mxx = fmaxf(fmaxf(xs.x, xs.y), fmaxf(xs.z, xs.w));
    float mny = fminf(fminf(ys.x, ys.y), fminf(ys.z, ys.w));
    float mxy = fmaxf(fmaxf(ys.x, ys.y), fmaxf(ys.z, ys.w));
    ((float4*)aabbA)[so] = make_float4(mnx, mny, mxx, mxy);
    areaA[so] = pr5[gi * 5 + 2] * pr5[gi * 5 + 3];
  }
  __syncthreads();
  if (tid == 0) gV[g] = cnt;
}

// ---------------------------------------------------------------------------
// exact convex quad-quad intersection area — register-resident, bit-identical
// float op order vs reference (fp contract off)
// ---------------------------------------------------------------------------
__device__ __forceinline__ float inter_area_reg(const float qx[4], const float qy[4],
                                                const float rx[4], const float ry[4]) {
  float px_[8], py_[8];
  #pragma unroll
  for (int t = 0; t < 8; ++t) { px_[t] = (t < 4) ? qx[t] : 0.f; py_[t] = (t < 4) ? qy[t] : 0.f; }
  int n = 4;
  #pragma unroll
  for (int e = 0; e < 4; ++e) {
    float a0 = rx[e], a1 = ry[e];
    float b0 = rx[(e + 1) & 3], b1 = ry[(e + 1) & 3];
    float dx = b0 - a0, dy = b1 - a1;
    float ox_[8], oy_[8];
    #pragma unroll
    for (int t = 0; t < 8; ++t) { ox_[t] = 0.f; oy_[t] = 0.f; }
    float cr[8];
    #pragma unroll
    for (int t = 0; t < 8; ++t) cr[t] = dx * (py_[t] - a1) - dy * (px_[t] - a0);
    int m = 0;
    int nn = (n > 1) ? n : 1;
    #pragma unroll
    for (int t = 0; t < 8; ++t) {
      bool act = t < n;
      float sx = px_[t], sy = py_[t];
      float ex, ey, ce;
      if (t == 7) { ex = px_[0]; ey = py_[0]; ce = cr[0]; }
      else {
        bool wrap = (t + 1 == nn);
        ex = wrap ? px_[0] : px_[t + 1];
        ey = wrap ? py_[0] : py_[t + 1];
        ce = wrap ? cr[0] : cr[t + 1];
      }
      float cs = cr[t];
      float denom = cs - ce;
      float dn = (fabsf(denom) > 1e-12f) ? denom : 1e-12f;
      float tt = cs / dn;
      float ipx = sx + tt * (ex - sx);
      float ipy = sy + tt * (ey - sy);
      bool s_in = cs >= 0.f, e_in = ce >= 0.f;
      bool app1 = act && (s_in != e_in);
      #pragma unroll
      for (int s2 = 0; s2 < 8; ++s2) {
        bool wr = app1 && (m == s2);
        ox_[s2] = wr ? ipx : ox_[s2];
        oy_[s2] = wr ? ipy : oy_[s2];
      }
      m += app1 ? 1 : 0;
      bool app2 = act && e_in;
      #pragma unroll
      for (int s2 = 0; s2 < 8; ++s2) {
        bool wr = app2 && (m == s2);
        ox_[s2] = wr ? ex : ox_[s2];
        oy_[s2] = wr ? ey : oy_[s2];
      }
      m += app2 ? 1 : 0;
    }
    n = m;
    #pragma unroll
    for (int t = 0; t < 8; ++t) { px_[t] = ox_[t]; py_[t] = oy_[t]; }
  }
  int nn = (n > 1) ? n : 1;
  float s = 0.f;
  #pragma unroll
  for (int t = 0; t < 8; ++t) {
    if (t < n) {
      float nx_x, nx_y;
      if (t == 7) { nx_x = px_[0]; nx_y = py_[0]; }
      else {
        bool wrap = (t + 1 == nn);
        nx_x = wrap ? px_[0] : px_[t + 1];
        nx_y = wrap ? py_[0] : py_[t + 1];
      }
      s += px_[t] * nx_y - nx_x * py_[t];
    }
  }
  float area = 0.5f * fabsf(s);
  return (n >= 3) ? area : 0.f;
}

// ---------------------------------------------------------------------------
// K3a: AABB-filter + LDS-compact + dense IoU over surviving pairs.
// grid = (128, 40); 256 thr x 4 pair-slots = 1024 pairs/block.
// ---------------------------------------------------------------------------
#define PPT 4
#define TPB 256
__global__ void pair_kernel(const int* __restrict__ gV,
                            const float* __restrict__ aabbA,
                            const float* __restrict__ areaA,
                            const float* __restrict__ ptsS,
                            u64* __restrict__ sup) {
  int g = blockIdx.y;
  int V = gV[g];
  long long Tp = (long long)V * (V - 1) / 2;
  long long base = (long long)blockIdx.x * (TPB * PPT);
  if (base >= Tp) return;
  __shared__ u32 q[TPB * PPT];
  __shared__ int qn;
  int tid = threadIdx.x;
  if (tid == 0) qn = 0;
  __syncthreads();
  const float4* ab = (const float4*)aabbA;
  for (int t = 0; t < PPT; ++t) {
    long long kk = base + t * TPB + tid;     // coalesced within wave
    if (kk >= Tp) break;
    float kf = (float)kk;
    int i = (int)((1.0f + sqrtf(1.0f + 8.0f * kf)) * 0.5f);
    while ((long long)i * (i - 1) / 2 > kk) --i;
    while ((long long)(i + 1) * i / 2 <= kk) ++i;
    int j = (int)(kk - (long long)i * (i - 1) / 2);
    float4 bi = ab[g * P_ + i];
    float4 bj = ab[g * P_ + j];
    bool ov = (bi.x <= bj.z) && (bj.x <= bi.z) && (bi.y <= bj.w) && (bj.y <= bi.w);
    if (ov) {
      int s = atomicAdd(&qn, 1);
      q[s] = (u32)((i << 9) | j);
    }
  }
  __syncthreads();
  int nq = qn;
  const float4* pS = (const float4*)ptsS;
  for (int s = tid; s < nq; s += TPB) {
    u32 pk = q[s];
    int i = (int)(pk >> 9), j = (int)(pk & 511);
    float4 ax = pS[(g * P_ + i) * 2];
    float4 ay = pS[(g * P_ + i) * 2 + 1];
    float4 bx = pS[(g * P_ + j) * 2];
    float4 by = pS[(g * P_ + j) * 2 + 1];
    float qx[4] = {ax.x, ax.y, ax.z, ax.w};
    float qy[4] = {ay.x, ay.y, ay.z, ay.w};
    float rx[4] = {bx.x, bx.y, bx.z, bx.w};
    float ry[4] = {by.x, by.y, by.z, by.w};
    float ai = areaA[g * P_ + i];
    float aj = areaA[g * P_ + j];
    // reference iou[i][j]: clip quad i by edges of quad j
    float inter = inter_area_reg(qx, qy, rx, ry);
    float iou = inter / (((ai + aj) - inter) + 1e-8f);
    if (iou > NMS_THR)
      atomicOr(&sup[((size_t)g * P_ + i) * 8 + (j >> 6)], 1ull << (j & 63));
  }
}

// ---------------------------------------------------------------------------
// K3b: sequential greedy over bitmasks (prefetched rows) + parallel emit of
// first 100 kept per group (popcount-prefix slots)
// ---------------------------------------------------------------------------
__global__ void greedy_kernel(const float* __restrict__ scs, const int* __restrict__ gV,
                              const u64* __restrict__ sup, u64* __restrict__ cand) {
  int g = blockIdx.x;
  int tid = threadIdx.x;   // 64
  __shared__ u64 lsup[P_ * 8];
  __shared__ u64 skeep[8];
  int V = gV[g];
  for (int w = tid; w < V * 8; w += 64) lsup[w] = sup[(size_t)g * P_ * 8 + w];
  __syncthreads();
  // lane t (t<8) owns word t of the keep mask
  u64 keepw = 0;
  u64 cur = (tid < 8 && V > 0) ? lsup[tid] : 0ull;
  for (int i = 0; i < V; ++i) {
    u64 nxt = (tid < 8 && (i + 1) < V) ? lsup[(i + 1) * 8 + tid] : 0ull;  // prefetch
    bool supd = __any((cur & keepw) != 0ull);
    if (!supd && tid == (i >> 6)) keepw |= 1ull << (i & 63);
    cur = nxt;
  }
  if (tid < 8) skeep[tid] = keepw;
  __syncthreads();
  int cls = g % CF;
  int tot = 0;
  #pragma unroll
  for (int t = 0; t < 8; ++t) tot += __popcll(skeep[t]);
  for (int r = tid; r < V; r += 64) {
    if ((skeep[r >> 6] >> (r & 63)) & 1ull) {
      int slot = __popcll(skeep[r >> 6] & ((1ull << (r & 63)) - 1ull));
      for (int t = 0; t < (r >> 6); ++t) slot += __popcll(skeep[t]);
      if (slot < DET) {
        float sv = scs[g * P_ + r];
        int flat = cls * P_ + r;
        cand[g * DET + slot] = ((u64)f2o(sv) << 32) | (u32)(~(u32)flat);
      }
    }
  }
  int fill = tot < DET ? tot : DET;
  for (int s = fill + tid; s < DET; s += 64) cand[g * DET + s] = 0ull;
}

// ---------------------------------------------------------------------------
// K4: per-image top-100 by RANK SELECTION (keys are globally distinct u64s;
// rank = #{keys > k}; rank<100 scatters straight to output row `rank`).
// out layout: bb[2,100,4] | rr[2,100,5] | sc[2,100] | lab[2,100] (all f32);
// zeros pre-filled by hipMemsetAsync.
// ---------------------------------------------------------------------------
#define NC (CF * DET)    // 2000 candidates per image
__global__ void rank_kernel(const u64* __restrict__ cand, const int* __restrict__ sord,
                            const float* __restrict__ pr5, const float* __restrict__ bb4,
                            float* __restrict__ out) {
  int b = blockIdx.y;
  int tid = threadIdx.x;
  __shared__ u64 ls[NC];
  for (int i = tid; i < NC; i += 256) ls[i] = cand[b * NC + i];
  __syncthreads();
  int ci = blockIdx.x * 256 + tid;
  u64 k = (ci < NC) ? ls[ci] : 0ull;
  if (k == 0ull) return;
  int rank = 0;
  #pragma unroll 8
  for (int s = 0; s < NC; ++s) rank += (ls[s] > k) ? 1 : 0;
  if (rank >= DET) return;
  float score = o2f((u32)(k >> 32));
  int flat = (int)(~(u32)k);
  int cls = flat >> 9, r = flat & (P_ - 1);
  int p = sord[(b * CF + cls) * P_ + r];
  int gi = (b * CF + cls) * P_ + p;
  int o_bb = (b * DET + rank) * 4;
  int o_rr = B_ * DET * 4 + (b * DET + rank) * 5;
  int o_sc = B_ * DET * 9 + b * DET + rank;
  int o_lab = B_ * DET * 10 + b * DET + rank;
  for (int q = 0; q < 4; ++q) out[o_bb + q] = bb4[gi * 4 + q];
  for (int q = 0; q < 5; ++q) out[o_rr + q] = pr5[gi * 5 + q];
  out[o_sc] = score;
  out[o_lab] = (float)(cls + 1);
}

// ---------------------------------------------------------------------------
extern "C" void kernel_launch(void* const* d_in, const int* in_sizes, int n_in,
                              void* d_out, int out_size, void* d_ws, size_t ws_size,
                              hipStream_t stream) {
  const float* logits = (const float*)d_in[0];
  const float* breg   = (const float*)d_in[1];
  const float* rrects = (const float*)d_in[2];
  float* out = (float*)d_out;

  const int G = B_ * CF;
  u64*   sup  = (u64*)d_ws;                          // G*512*8 u64 = 1.31 MB
  u64*   cand = sup + (size_t)G * P_ * 8;            // 4000 u64
  int*   gV   = (int*)(cand + G * DET);              // 64 ints (padded)
  float* smsk = (float*)(gV + 64);
  float* scs  = smsk + G * P_;
  int*   sord = (int*)(scs + G * P_);
  float* pr5  = (float*)(sord + G * P_);
  float* bb4  = pr5 + (size_t)G * P_ * 5;
  float* pts8 = bb4 + (size_t)G * P_ * 4;
  float* ptsS = pts8 + (size_t)G * P_ * 8;
  float* aabbA = ptsS + (size_t)G * P_ * 8;
  float* areaA = aabbA + (size_t)G * P_ * 4;

  hipMemsetAsync(d_out, 0, (size_t)out_size * sizeof(float), stream);

  int total = B_ * P_ * CF;
  decode_kernel<<<(total + 255) / 256, 256, 0, stream>>>(logits, breg, rrects,
                                                         smsk, pr5, bb4, pts8);
  sort_kernel<<<G, 256, 0, stream>>>(smsk, pts8, pr5, scs, sord, gV,
                                     ptsS, aabbA, areaA, sup);
  pair_kernel<<<dim3(128, G), TPB, 0, stream>>>(gV, aabbA, areaA, ptsS, sup);
  greedy_kernel<<<G, 64, 0, stream>>>(scs, gV, sup, cand);
  rank_kernel<<<dim3((NC + 255) / 256, B_), 256, 0, stream>>>(cand, sord, pr5, bb4, out);
}